// Round 1
// baseline (7091.140 us; speedup 1.0000x reference)
//
#include <hip/hip_runtime.h>
#include <cmath>

#define CLIPV 20.0f
#define EPSV 1e-6f

__device__ __forceinline__ float sigmoidf_(float x){ return 1.0f/(1.0f + expf(-x)); }
__device__ __forceinline__ float softplusf_(float x){ return (x > 20.0f) ? x : log1pf(expf(x)); }
__device__ __forceinline__ float clipf_(float x){ return fminf(fmaxf(x, -CLIPV), CLIPV); }

__device__ __forceinline__ float wave_sum64(float v){
  #pragma unroll
  for (int off=32; off>=1; off>>=1) v += __shfl_xor(v, off, 64);
  return v;
}
__device__ __forceinline__ float wave_max64(float v){
  #pragma unroll
  for (int off=32; off>=1; off>>=1) v = fmaxf(v, __shfl_xor(v, off, 64));
  return v;
}
__device__ __forceinline__ float block_sum256(float v, float* s_red){
  v = wave_sum64(v);
  __syncthreads();
  if ((threadIdx.x & 63) == 0) s_red[threadIdx.x>>6] = v;
  __syncthreads();
  return s_red[0]+s_red[1]+s_red[2]+s_red[3];
}
__device__ __forceinline__ float block_max256(float v, float* s_red){
  v = wave_max64(v);
  __syncthreads();
  if ((threadIdx.x & 63) == 0) s_red[threadIdx.x>>6] = v;
  __syncthreads();
  return fmaxf(fmaxf(s_red[0],s_red[1]), fmaxf(s_red[2],s_red[3]));
}

// ------------------------- embedding: qv = tanh(emb[qst]) -------------------------
__global__ void embed_kernel(const int* __restrict__ qst, const float* __restrict__ emb,
                             float* __restrict__ qv){
  int idx = blockIdx.x*256 + threadIdx.x;
  if (idx >= 64*20*300) return;
  int b = idx / 6000;
  int rem = idx - b*6000;
  int t = rem / 300;
  int e = rem - t*300;
  int tok = qst[b*20 + t];
  qv[idx] = tanhf(emb[(size_t)tok*300 + e]);
}

// ------------------------- generic tiled f32 GEMM, M=64, up to 3 segments ---------
// mode: 0 = write split-K partial; 1 = bias+store; 2 = bias+clip, accumulate into out;
//       3 = bias+clip+tanh, store
template<int BN, int TN>
__global__ __launch_bounds__(256) void gemm_f32(
    int N, int Ktot, int KS,
    const float* __restrict__ A0, int lda0, const float* __restrict__ B0, int K0,
    const float* __restrict__ A1, int lda1, const float* __restrict__ B1, int K1,
    const float* __restrict__ A2, int lda2, const float* __restrict__ B2, int K2,
    const float* __restrict__ bias, float* __restrict__ out, int ldo, int mode,
    float* __restrict__ part)
{
  const int KT = 16;
  __shared__ float As[KT][64];
  __shared__ float Bs[KT][BN];
  int tid = threadIdx.x;
  int tm = tid >> 4, tn = tid & 15;
  int nb = blockIdx.x * BN;
  int ks = blockIdx.y;
  int Kc = (Ktot + KS - 1)/KS;
  int kbeg = ks*Kc, kend = min(Ktot, kbeg + Kc);
  int K01 = K0 + K1;

  float acc[4][TN];
  #pragma unroll
  for (int i=0;i<4;i++)
    #pragma unroll
    for (int j=0;j<TN;j++) acc[i][j] = 0.f;

  for (int k0 = kbeg; k0 < kend; k0 += KT){
    for (int e = tid; e < 64*KT; e += 256){
      int m = e >> 4, kk = e & 15;
      int k = k0 + kk;
      float v = 0.f;
      if (k < kend){
        if (k < K0)        v = A0[(size_t)m*lda0 + k];
        else if (k < K01)  v = A1[(size_t)m*lda1 + (k - K0)];
        else               v = A2[(size_t)m*lda2 + (k - K01)];
      }
      As[kk][m] = v;
    }
    for (int e = tid; e < BN*KT; e += 256){
      int kk = e / BN, n = e - kk*BN;
      int k = k0 + kk;
      int ng = nb + n;
      float v = 0.f;
      if (k < kend && ng < N){
        if (k < K0)        v = B0[(size_t)k*N + ng];
        else if (k < K01)  v = B1[(size_t)(k-K0)*N + ng];
        else               v = B2[(size_t)(k-K01)*N + ng];
      }
      Bs[kk][n] = v;
    }
    __syncthreads();
    #pragma unroll
    for (int kk = 0; kk < KT; kk++){
      float av[4];
      #pragma unroll
      for (int i=0;i<4;i++) av[i] = As[kk][4*tm+i];
      float bv[TN];
      #pragma unroll
      for (int j=0;j<TN;j++) bv[j] = Bs[kk][TN*tn+j];
      #pragma unroll
      for (int i=0;i<4;i++)
        #pragma unroll
        for (int j=0;j<TN;j++)
          acc[i][j] += av[i]*bv[j];
    }
    __syncthreads();
  }

  #pragma unroll
  for (int i=0;i<4;i++){
    int m = 4*tm + i;
    #pragma unroll
    for (int j=0;j<TN;j++){
      int n = nb + TN*tn + j;
      if (n < N){
        if (mode == 0){
          part[(size_t)ks*64*N + (size_t)m*N + n] = acc[i][j];
        } else {
          float v = acc[i][j] + bias[n];
          if (mode == 1)      out[(size_t)m*ldo + n] = v;
          else if (mode == 2) out[(size_t)m*ldo + n] += clipf_(v);
          else                out[(size_t)m*ldo + n] = tanhf(clipf_(v));
        }
      }
    }
  }
}

// ------------------------- split-K reduce (+bias, optional tanh) ------------------
__global__ void reduce_bias_kernel(const float* __restrict__ part, int KS, int N,
                                   const float* __restrict__ bias, float* __restrict__ out,
                                   int mode){
  int idx = blockIdx.x*256 + threadIdx.x;
  if (idx >= 64*N) return;
  int n = idx % N;
  float v = bias[n];
  for (int p=0; p<KS; p++) v += part[(size_t)p*64*N + idx];
  if (mode == 1) v = tanhf(v);
  out[idx] = v;
}

// ------------------------- LSTM cell (reduces gate split-K partials) --------------
__global__ void lstm_kernel(const float* __restrict__ gp, int KS, const float* __restrict__ bias,
                            float* __restrict__ h, float* __restrict__ c, float* __restrict__ hc){
  int idx = blockIdx.x*256 + threadIdx.x;
  if (idx >= 64*512) return;
  int b = idx >> 9, j = idx & 511;
  float gi = bias[j], gf = bias[512+j], gg = bias[1024+j], go = bias[1536+j];
  for (int p=0; p<KS; p++){
    const float* g = gp + (size_t)p*64*2048 + (size_t)b*2048;
    gi += g[j]; gf += g[512+j]; gg += g[1024+j]; go += g[1536+j];
  }
  float cn = sigmoidf_(gf)*c[idx] + sigmoidf_(gi)*tanhf(gg);
  float hn = sigmoidf_(go)*tanhf(cn);
  c[idx] = cn; h[idx] = hn; hc[idx] = clipf_(hn);
}

// ------------------------- comb = tanh(l2norm(imgf) * qsum/20) --------------------
__global__ __launch_bounds__(256) void comb_kernel(const float* __restrict__ imgf,
                                                   const float* __restrict__ qsum,
                                                   float* __restrict__ comb){
  __shared__ float s_red[4];
  int b = blockIdx.x, tid = threadIdx.x;
  float ss = 0.f;
  for (int j = tid; j < 1024; j += 256){ float v = imgf[b*1024+j]; ss += v*v; }
  ss = wave_sum64(ss);
  if ((tid & 63) == 0) s_red[tid>>6] = ss;
  __syncthreads();
  float inv = 1.0f / sqrtf(s_red[0]+s_red[1]+s_red[2]+s_red[3]);
  for (int j = tid; j < 1024; j += 256)
    comb[b*1024+j] = tanhf(imgf[b*1024+j]*inv * qsum[b*1024+j]*0.05f);
}

// ------------------------- last[:,1024:1280] = tanh(rvec) -------------------------
__global__ void tanhcopy_kernel(const float* __restrict__ rvec, float* __restrict__ last){
  int idx = blockIdx.x*256 + threadIdx.x;
  if (idx >= 64*256) return;
  int b = idx >> 8, i = idx & 255;
  last[(size_t)b*1280 + 1024 + i] = tanhf(rvec[idx]);
}

// ------------------------- fused DNC memory step (one block per sample) -----------
__global__ __launch_bounds__(256) void dnc_mem_kernel(
    const float* __restrict__ xi,
    float* __restrict__ mem, float* __restrict__ link,
    const float* __restrict__ prec_in, float* __restrict__ prec_out,
    float* __restrict__ wr, float* __restrict__ ww,
    float* __restrict__ usage, float* __restrict__ rvec)
{
  __shared__ float s_rk[4*64], s_rstr[4], s_wkey[64], s_erase[64], s_wvec[64];
  __shared__ float s_free[4], s_modes[12], s_scal[3];
  __shared__ float s_wr[4*256], s_vB[4*256];
  __shared__ float s_wwold[256], s_wwnew[256], s_usage[256], s_prec[256];
  __shared__ float s_alloc[256], s_scan[256];
  __shared__ int   s_rank[256];
  __shared__ float s_sim[4*256];
  __shared__ float s_fwA[4*256], s_fwB[4*256], s_C[4*256], s_D[4*256];
  __shared__ float s_red[4];
  __shared__ float s_PQ[8];

  int tid = threadIdx.x;
  int b = blockIdx.x;
  int lane = tid & 63, wid = tid >> 6;

  // ---- Stage 1: parse interface vector, load states, zero C/D ----
  const float* xrow = xi + (size_t)b*471;
  for (int idx = tid; idx < 471; idx += 256){
    float v = xrow[idx];
    if (idx < 256)       s_rk[idx] = tanhf(v);
    else if (idx < 260)  s_rstr[idx-256] = softplusf_(v);
    else if (idx < 324)  s_wkey[idx-260] = v;               // raw, normalize below
    else if (idx == 324) s_scal[0] = softplusf_(v);         // write strength
    else if (idx < 389)  s_erase[idx-325] = sigmoidf_(v);
    else if (idx < 453)  s_wvec[idx-389] = tanhf(v);
    else if (idx < 457)  s_free[idx-453] = sigmoidf_(v);
    else if (idx == 457) s_scal[1] = sigmoidf_(v);          // alloc gate
    else if (idx == 458) s_scal[2] = sigmoidf_(v);          // write gate
    else                 s_modes[idx-459] = v;              // raw, softmax below
  }
  for (int e = tid; e < 1024; e += 256){
    s_wr[e] = wr[(size_t)b*1024 + e];
    s_C[e] = 0.f; s_D[e] = 0.f;
  }
  s_wwold[tid] = ww[(size_t)b*256 + tid];
  s_usage[tid] = usage[(size_t)b*256 + tid];
  s_prec[tid]  = prec_in[(size_t)b*256 + tid];
  __syncthreads();

  // modes softmax (threads 0..3)
  if (tid < 4){
    float m0 = s_modes[tid*3], m1 = s_modes[tid*3+1], m2 = s_modes[tid*3+2];
    float mx = fmaxf(m0, fmaxf(m1,m2));
    float e0 = expf(m0-mx), e1 = expf(m1-mx), e2 = expf(m2-mx);
    float s = e0+e1+e2;
    s_modes[tid*3] = e0/s; s_modes[tid*3+1] = e1/s; s_modes[tid*3+2] = e2/s;
  }
  // read keys normalize: wave wid handles r = wid (own region, no cross-wave hazard)
  {
    float k = s_rk[wid*64 + lane];
    float ss = wave_sum64(k*k);
    s_rk[wid*64 + lane] = k / (sqrtf(ss) + EPSV);
  }
  // write key normalize: wave 0 only
  if (wid == 0){
    float k = s_wkey[lane];
    float ss = wave_sum64(k*k);
    s_wkey[lane] = k / (sqrtf(ss) + EPSV);
  }

  // ---- Stage 2: usage update ----
  {
    float psi = 1.f;
    #pragma unroll
    for (int r=0;r<4;r++) psi *= (1.f - s_free[r]*s_wr[r*256+tid]);
    float u = (s_usage[tid] + s_wwold[tid] - s_usage[tid]*s_wwold[tid]) * psi;
    s_usage[tid] = u;
    usage[(size_t)b*256 + tid] = u;
  }
  __syncthreads();

  // ---- Stage 3: stable ascending rank (matches stable argsort) ----
  {
    float u = s_usage[tid];
    int rank = 0;
    for (int j=0;j<256;j++){
      float uj = s_usage[j];
      rank += (uj < u) || (uj == u && j < tid);
    }
    s_rank[tid] = rank;
    s_scan[rank] = u;       // sorted usage
  }
  __syncthreads();

  // ---- Stage 4: inclusive product scan over sorted usage ----
  for (int off=1; off<256; off<<=1){
    float t = (tid >= off) ? s_scan[tid-off] : 1.f;
    __syncthreads();
    s_scan[tid] *= t;
    __syncthreads();
  }
  {
    float u = s_usage[tid];
    int rk = s_rank[tid];
    float cpe = (rk > 0) ? s_scan[rk-1] : 1.f;   // exclusive cumprod
    s_alloc[tid] = (1.f - u) * cpe;
  }

  // ---- Stage 5: write-key cosine similarity (wave-per-row) ----
  for (int i = 0; i < 64; i++){
    int n = wid*64 + i;
    float m = mem[(size_t)b*16384 + (size_t)n*64 + lane];
    float s1 = wave_sum64(m*m);
    float s2 = wave_sum64(m*s_wkey[lane]);
    if (lane == 0) s_sim[n] = s2 / (sqrtf(s1)+EPSV) * s_scal[0];
  }
  __syncthreads();

  // ---- Stage 6: write softmax, ww, prec, vB, P, Q ----
  {
    float v = s_sim[tid];
    float mx = block_max256(v, s_red);
    float e = expf(v - mx);
    float sm = block_sum256(e, s_red);
    float cw = e / sm;
    float wwn = s_scal[2] * (s_scal[1]*s_alloc[tid] + (1.f - s_scal[1])*cw);
    s_wwnew[tid] = wwn;
    ww[(size_t)b*256 + tid] = wwn;
    #pragma unroll
    for (int r=0;r<4;r++) s_vB[r*256+tid] = wwn * s_wr[r*256+tid];
    float wws = block_sum256(wwn, s_red);
    prec_out[(size_t)b*256 + tid] = (1.f - wws)*s_prec[tid] + wwn;
    #pragma unroll
    for (int r=0;r<4;r++){
      float pv = block_sum256(s_prec[tid]*s_wr[r*256+tid], s_red);
      float qv_ = block_sum256(wwn*s_wr[r*256+tid], s_red);
      if (tid == 0){ s_PQ[r] = pv; s_PQ[4+r] = qv_; }
    }
  }
  __syncthreads();

  // ---- Stage 7: memory update (float4) ----
  {
    float4* mem4 = (float4*)(mem + (size_t)b*16384);
    for (int e4 = tid; e4 < 4096; e4 += 256){
      int n = e4 >> 4;
      int w0 = (e4 & 15) << 2;
      float4 mv = mem4[e4];
      float wwn = s_wwnew[n];
      mv.x = mv.x*(1.f - wwn*s_erase[w0+0]) + wwn*s_wvec[w0+0];
      mv.y = mv.y*(1.f - wwn*s_erase[w0+1]) + wwn*s_wvec[w0+1];
      mv.z = mv.z*(1.f - wwn*s_erase[w0+2]) + wwn*s_wvec[w0+2];
      mv.w = mv.w*(1.f - wwn*s_erase[w0+3]) + wwn*s_wvec[w0+3];
      mem4[e4] = mv;
    }
  }
  __syncthreads();

  // ---- Stage 8a: A,B row-sums against OLD link (thread = row) ----
  {
    const float4* Lrow = (const float4*)(link + (size_t)b*65536 + (size_t)tid*256);
    float aA[4] = {0,0,0,0}, aB[4] = {0,0,0,0};
    for (int c4 = 0; c4 < 64; c4++){
      float4 lv = Lrow[c4];
      int j = c4*4;
      #pragma unroll
      for (int r=0;r<4;r++){
        aA[r] += lv.x*s_wr[r*256+j] + lv.y*s_wr[r*256+j+1] + lv.z*s_wr[r*256+j+2] + lv.w*s_wr[r*256+j+3];
        aB[r] += lv.x*s_vB[r*256+j] + lv.y*s_vB[r*256+j+1] + lv.z*s_vB[r*256+j+2] + lv.w*s_vB[r*256+j+3];
      }
    }
    #pragma unroll
    for (int r=0;r<4;r++){ s_fwA[r*256+tid] = aA[r]; s_fwB[r*256+tid] = aB[r]; }
  }
  __syncthreads();

  // ---- Stage 8b: link update + C,D col-sums (coalesced, float4) ----
  {
    int cg = tid & 63, ioff = tid >> 6;
    int j0 = cg*4;
    float wwj0 = s_wwnew[j0], wwj1 = s_wwnew[j0+1], wwj2 = s_wwnew[j0+2], wwj3 = s_wwnew[j0+3];
    float pj0 = s_prec[j0], pj1 = s_prec[j0+1], pj2 = s_prec[j0+2], pj3 = s_prec[j0+3];
    float cC[4][4] = {{0}}, cD[4][4] = {{0}};
    float4* Lb = (float4*)(link + (size_t)b*65536);
    for (int it = 0; it < 64; it++){
      int i = it*4 + ioff;
      float4 lv = Lb[(size_t)i*64 + cg];
      float wwi = s_wwnew[i];
      float4 ln;
      ln.x = (1.f - wwi - wwj0)*lv.x + wwi*pj0;
      ln.y = (1.f - wwi - wwj1)*lv.y + wwi*pj1;
      ln.z = (1.f - wwi - wwj2)*lv.z + wwi*pj2;
      ln.w = (1.f - wwi - wwj3)*lv.w + wwi*pj3;
      if (i >= j0 && i < j0+4){
        if (i == j0)        ln.x = 0.f;
        else if (i == j0+1) ln.y = 0.f;
        else if (i == j0+2) ln.z = 0.f;
        else                ln.w = 0.f;
      }
      Lb[(size_t)i*64 + cg] = ln;
      #pragma unroll
      for (int r=0;r<4;r++){
        float wri = s_wr[r*256+i], vbi = s_vB[r*256+i];
        cC[r][0] += lv.x*wri; cC[r][1] += lv.y*wri; cC[r][2] += lv.z*wri; cC[r][3] += lv.w*wri;
        cD[r][0] += lv.x*vbi; cD[r][1] += lv.y*vbi; cD[r][2] += lv.z*vbi; cD[r][3] += lv.w*vbi;
      }
    }
    for (int w=0; w<4; w++){
      if (ioff == w){
        #pragma unroll
        for (int r=0;r<4;r++){
          s_C[r*256+j0+0] += cC[r][0]; s_C[r*256+j0+1] += cC[r][1];
          s_C[r*256+j0+2] += cC[r][2]; s_C[r*256+j0+3] += cC[r][3];
          s_D[r*256+j0+0] += cD[r][0]; s_D[r*256+j0+1] += cD[r][1];
          s_D[r*256+j0+2] += cD[r][2]; s_D[r*256+j0+3] += cD[r][3];
        }
      }
      __syncthreads();
    }
  }

  // ---- Stage 9: read-key cosine on UPDATED mem (thread = row) ----
  {
    const float4* Mrow = (const float4*)(mem + (size_t)b*16384 + (size_t)tid*64);
    float nrm2 = 0.f, d0=0.f, d1=0.f, d2=0.f, d3=0.f;
    for (int c4=0; c4<16; c4++){
      float4 mv = Mrow[c4];
      int w0 = c4*4;
      nrm2 += mv.x*mv.x + mv.y*mv.y + mv.z*mv.z + mv.w*mv.w;
      d0 += mv.x*s_rk[w0] + mv.y*s_rk[w0+1] + mv.z*s_rk[w0+2] + mv.w*s_rk[w0+3];
      d1 += mv.x*s_rk[64+w0] + mv.y*s_rk[64+w0+1] + mv.z*s_rk[64+w0+2] + mv.w*s_rk[64+w0+3];
      d2 += mv.x*s_rk[128+w0] + mv.y*s_rk[128+w0+1] + mv.z*s_rk[128+w0+2] + mv.w*s_rk[128+w0+3];
      d3 += mv.x*s_rk[192+w0] + mv.y*s_rk[192+w0+1] + mv.z*s_rk[192+w0+2] + mv.w*s_rk[192+w0+3];
    }
    float inv = 1.f/(sqrtf(nrm2)+EPSV);
    s_sim[0*256+tid] = d0*inv*s_rstr[0];
    s_sim[1*256+tid] = d1*inv*s_rstr[1];
    s_sim[2*256+tid] = d2*inv*s_rstr[2];
    s_sim[3*256+tid] = d3*inv*s_rstr[3];
  }
  __syncthreads();
  for (int r=0;r<4;r++){
    float v = s_sim[r*256+tid];
    float mx = block_max256(v, s_red);
    float e = expf(v - mx);
    float sm = block_sum256(e, s_red);
    s_sim[r*256+tid] = e/sm;   // own element only
  }
  __syncthreads();

  // ---- Stage 10: fw/bw assembly + wr update ----
  {
    float wwn = s_wwnew[tid], pn = s_prec[tid];
    #pragma unroll
    for (int r=0;r<4;r++){
      float wro = s_wr[r*256+tid];
      float fw  = (1.f-wwn)*s_fwA[r*256+tid] - s_fwB[r*256+tid] + wwn*(s_PQ[r] - pn*wro);
      float bwv = (1.f-wwn)*s_C[r*256+tid]   - s_D[r*256+tid]   + pn*(s_PQ[4+r] - wwn*wro);
      float wrn = s_modes[r*3+0]*bwv + s_modes[r*3+1]*s_sim[r*256+tid] + s_modes[r*3+2]*fw;
      wr[(size_t)b*1024 + r*256 + tid] = wrn;
      s_vB[r*256+tid] = wrn;   // reuse as new-wr buffer
    }
  }
  __syncthreads();

  // ---- Stage 11: rvec = wr_new @ mem ----
  {
    int r = tid >> 6, w = tid & 63;
    const float* Mb = mem + (size_t)b*16384;
    float acc = 0.f;
    for (int n=0; n<256; n++) acc += s_vB[r*256+n]*Mb[(size_t)n*64 + w];
    rvec[(size_t)b*256 + r*64 + w] = acc;
  }
}

// ======================================================================================
extern "C" void kernel_launch(void* const* d_in, const int* in_sizes, int n_in,
                              void* d_out, int out_size, void* d_ws, size_t ws_size,
                              hipStream_t stream) {
  const float* img_feat = (const float*)d_in[0];
  const int*   qst      = (const int*)  d_in[1];
  const float* emb      = (const float*)d_in[2];
  const float* img_W    = (const float*)d_in[3];
  const float* img_b    = (const float*)d_in[4];
  const float* q_Wih    = (const float*)d_in[5];
  const float* q_Whh    = (const float*)d_in[6];
  const float* q_b      = (const float*)d_in[7];
  const float* q_Wif    = (const float*)d_in[8];
  const float* q_bif    = (const float*)d_in[9];
  const float* q_Wout   = (const float*)d_in[10];
  const float* q_bout   = (const float*)d_in[11];
  const float* c_Wih    = (const float*)d_in[12];
  const float* c_Whh    = (const float*)d_in[13];
  const float* c_b      = (const float*)d_in[14];
  const float* c_Wif    = (const float*)d_in[15];
  const float* c_bif    = (const float*)d_in[16];
  const float* c_Wout   = (const float*)d_in[17];
  const float* c_bout   = (const float*)d_in[18];
  const float* fc1_W    = (const float*)d_in[19];
  const float* fc1_b    = (const float*)d_in[20];
  const float* fc2_W    = (const float*)d_in[21];
  const float* fc2_b    = (const float*)d_in[22];

  float* ws = (float*)d_ws;
  // ---- workspace layout (floats) ----
  const size_t MEM_OFF   = 0;
  const size_t LINK_OFF  = 1048576;
  const size_t PREC0_OFF = 5242880;
  const size_t PREC1_OFF = 5259264;
  const size_t WR_OFF    = 5275648;
  const size_t WW_OFF    = 5341184;
  const size_t USAGE_OFF = 5357568;
  const size_t RVEC_OFF  = 5373952;
  const size_t H_OFF     = 5390336;
  const size_t C_OFF     = 5423104;
  const size_t QSUM_OFF  = 5455872;
  const size_t QV_OFF    = 5521408;
  const size_t GP_OFF    = 5905408;
  const size_t HC_OFF    = 6429696;
  const size_t XI_OFF    = 6462464;
  const size_t IMGF_OFF  = 6492608;
  const size_t IMGP_OFF  = 6558144;
  const size_t FC2P_OFF  = QV_OFF;        // overlay: dead buffers by fc2 time
  const size_t COMB_OFF  = 6820288;
  const size_t LAST_OFF  = 6885824;
  const size_t FC1P_OFF  = 6967744;
  const size_t HID1_OFF  = 7351744;

  float* memS  = ws + MEM_OFF;
  float* linkS = ws + LINK_OFF;
  float* prec0 = ws + PREC0_OFF;
  float* prec1 = ws + PREC1_OFF;
  float* wrS   = ws + WR_OFF;
  float* wwS   = ws + WW_OFF;
  float* usgS  = ws + USAGE_OFF;
  float* rvecS = ws + RVEC_OFF;
  float* hS    = ws + H_OFF;
  float* cS    = ws + C_OFF;
  float* qsum  = ws + QSUM_OFF;
  float* qv    = ws + QV_OFF;
  float* gp    = ws + GP_OFF;
  float* hcS   = ws + HC_OFF;
  float* xiB   = ws + XI_OFF;
  float* imgf  = ws + IMGF_OFF;
  float* imgp  = ws + IMGP_OFF;
  float* fc2p  = ws + FC2P_OFF;
  float* combB = ws + COMB_OFF;
  float* lastB = ws + LAST_OFF;
  float* fc1p  = ws + FC1P_OFF;
  float* hid1  = ws + HID1_OFF;

  // zero states + qsum
  hipMemsetAsync(ws, 0, (size_t)5521408*4, stream);

  // qv = tanh(emb[qst])
  embed_kernel<<<1500, 256, 0, stream>>>(qst, emb, qv);

  // image fc: imgf = img_feat @ img_W + img_b   (split-K=4)
  gemm_f32<64,4><<<dim3(16,4), 256, 0, stream>>>(1024, 4096, 4,
      img_feat, 4096, img_W, 4096,
      nullptr, 0, nullptr, 0, nullptr, 0, nullptr, 0,
      nullptr, nullptr, 0, 0, imgp);
  reduce_bias_kernel<<<256, 256, 0, stream>>>(imgp, 4, 1024, img_b, imgf, 0);

  // -------- question DNC, 20 steps --------
  for (int t = 0; t < 20; t++){
    gemm_f32<64,4><<<dim3(32,4), 256, 0, stream>>>(2048, 1068, 4,
        qv + t*300, 6000, q_Wih, 300,
        rvecS, 256, q_Wih + (size_t)300*2048, 256,
        hS, 512, q_Whh, 512,
        nullptr, nullptr, 0, 0, gp);
    lstm_kernel<<<128, 256, 0, stream>>>(gp, 4, q_b, hS, cS, hcS);
    gemm_f32<32,2><<<dim3(15,1), 256, 0, stream>>>(471, 512, 1,
        hcS, 512, q_Wif, 512,
        nullptr, 0, nullptr, 0, nullptr, 0, nullptr, 0,
        q_bif, xiB, 471, 1, nullptr);
    float* pin  = (t & 1) ? prec1 : prec0;
    float* pout = (t & 1) ? prec0 : prec1;
    dnc_mem_kernel<<<64, 256, 0, stream>>>(xiB, memS, linkS, pin, pout, wrS, wwS, usgS, rvecS);
    gemm_f32<32,2><<<dim3(32,1), 256, 0, stream>>>(1024, 768, 1,
        hcS, 512, q_Wout, 512,
        rvecS, 256, q_Wout + (size_t)512*1024, 256,
        nullptr, 0, nullptr, 0,
        q_bout, qsum, 1024, 2, nullptr);   // clip + accumulate (mean pool)
  }

  // comb = tanh(l2norm(imgf) * qsum/20)
  comb_kernel<<<64, 256, 0, stream>>>(imgf, qsum, combB);

  // reset DNC state for controller
  hipMemsetAsync(ws, 0, (size_t)5455872*4, stream);

  // -------- controller DNC, 1 step --------
  gemm_f32<64,4><<<dim3(32,4), 256, 0, stream>>>(2048, 1792, 4,
      combB, 1024, c_Wih, 1024,
      rvecS, 256, c_Wih + (size_t)1024*2048, 256,
      hS, 512, c_Whh, 512,
      nullptr, nullptr, 0, 0, gp);
  lstm_kernel<<<128, 256, 0, stream>>>(gp, 4, c_b, hS, cS, hcS);
  gemm_f32<32,2><<<dim3(15,1), 256, 0, stream>>>(471, 512, 1,
      hcS, 512, c_Wif, 512,
      nullptr, 0, nullptr, 0, nullptr, 0, nullptr, 0,
      c_bif, xiB, 471, 1, nullptr);
  dnc_mem_kernel<<<64, 256, 0, stream>>>(xiB, memS, linkS, prec0, prec1, wrS, wwS, usgS, rvecS);
  gemm_f32<32,2><<<dim3(32,1), 256, 0, stream>>>(1024, 768, 1,
      hcS, 512, c_Wout, 512,
      rvecS, 256, c_Wout + (size_t)512*1024, 256,
      nullptr, 0, nullptr, 0,
      c_bout, lastB, 1280, 3, nullptr);    // tanh(clip(out_c)) -> last[:, :1024]
  tanhcopy_kernel<<<64, 256, 0, stream>>>(rvecS, lastB);  // last[:, 1024:]

  // fc1: tanh(last @ fc1_W + fc1_b)
  gemm_f32<64,4><<<dim3(47,2), 256, 0, stream>>>(3000, 1280, 2,
      lastB, 1280, fc1_W, 1280,
      nullptr, 0, nullptr, 0, nullptr, 0, nullptr, 0,
      nullptr, nullptr, 0, 0, fc1p);
  reduce_bias_kernel<<<750, 256, 0, stream>>>(fc1p, 2, 3000, fc1_b, hid1, 1);

  // fc2: hid1 @ fc2_W + fc2_b -> logits
  gemm_f32<64,4><<<dim3(47,6), 256, 0, stream>>>(3000, 3000, 6,
      hid1, 3000, fc2_W, 3000,
      nullptr, 0, nullptr, 0, nullptr, 0, nullptr, 0,
      nullptr, nullptr, 0, 0, fc2p);
  reduce_bias_kernel<<<750, 256, 0, stream>>>(fc2p, 6, 3000, fc2_b, (float*)d_out, 0);
}

// Round 2
// 5224.415 us; speedup vs baseline: 1.3573x; 1.3573x over previous
//
#include <hip/hip_runtime.h>
#include <cmath>

#define CLIPV 20.0f
#define EPSV 1e-6f

__device__ __forceinline__ float sigmoidf_(float x){ return 1.0f/(1.0f + expf(-x)); }
__device__ __forceinline__ float softplusf_(float x){ return (x > 20.0f) ? x : log1pf(expf(x)); }
__device__ __forceinline__ float clipf_(float x){ return fminf(fmaxf(x, -CLIPV), CLIPV); }

__device__ __forceinline__ float wave_sum64(float v){
  #pragma unroll
  for (int off=32; off>=1; off>>=1) v += __shfl_xor(v, off, 64);
  return v;
}
__device__ __forceinline__ float wave_max64(float v){
  #pragma unroll
  for (int off=32; off>=1; off>>=1) v = fmaxf(v, __shfl_xor(v, off, 64));
  return v;
}
__device__ __forceinline__ float block_sum256(float v, float* s_red){
  v = wave_sum64(v);
  __syncthreads();
  if ((threadIdx.x & 63) == 0) s_red[threadIdx.x>>6] = v;
  __syncthreads();
  return s_red[0]+s_red[1]+s_red[2]+s_red[3];
}
__device__ __forceinline__ float block_max256(float v, float* s_red){
  v = wave_max64(v);
  __syncthreads();
  if ((threadIdx.x & 63) == 0) s_red[threadIdx.x>>6] = v;
  __syncthreads();
  return fmaxf(fmaxf(s_red[0],s_red[1]), fmaxf(s_red[2],s_red[3]));
}

// ---- workspace layout (float offsets), shared host/device ----
#define WS_MEM    0
#define WS_LINK   1048576
#define WS_PREC   5242880   /* 2 x 16384 */
#define WS_WR     5275648
#define WS_WW     5341184
#define WS_USAGE  5357568
#define WS_RVECT  5373952   /* transposed [256][64] */
#define WS_HT     5390336   /* 2 x [512][64] */
#define WS_HCT    5455872   /* 2 x [512][64] */
#define WS_XI     5521408   /* [64][471] */
#define WS_QSUM   5551552   /* [64][1024] */
#define WS_BAR    5617088   /* int counter */
#define WS_ZONEA  5617152   /* memset extent */
#define WS_QV     5617152   /* [1280][300] */
#define WS_ZONEC  6001152   /* 2,621,440: img-part / gxp / cxp(+part) / fc-parts */
#define WS_IMGF   8622592   /* [64][1024] */
#define WS_COMB   8688128
#define WS_LASTB  8753664   /* [64][1280] */
#define WS_HID1   8835584   /* [64][3000] */

// ------------------------- embedding: qv[(t*64+b)*300+e] = tanh(emb[qst]) ---------
__global__ void embed_kernel(const int* __restrict__ qst, const float* __restrict__ emb,
                             float* __restrict__ qv){
  int idx = blockIdx.x*256 + threadIdx.x;
  if (idx >= 1280*300) return;
  int m = idx / 300;
  int e = idx - m*300;
  int t = m >> 6, b = m & 63;
  int tok = qst[b*20 + t];
  qv[idx] = tanhf(emb[(size_t)tok*300 + e]);
}

// ------------------------- generic tiled f32 GEMM (float4 loads) ------------------
// A [M x K] row-major lda, B [K x N] row-major. grid (ceil(N/64), KS, M/64).
// mode 0: part[ks][64][N] split-K partial; 1: out=v(+bias); 2: out=tanh(v+bias)
__global__ __launch_bounds__(256) void gemm64(
    int M, int N, int Ktot, int KS,
    const float* __restrict__ A, int lda,
    const float* __restrict__ B,
    const float* __restrict__ bias,
    float* __restrict__ out, float* __restrict__ part, int mode)
{
  __shared__ float As[32*68];
  __shared__ float Bs[32*68];
  int tid = threadIdx.x;
  int nb = blockIdx.x*64, ks = blockIdx.y, mb = blockIdx.z*64;
  int Kc = (((Ktot + KS - 1)/KS) + 3) & ~3;
  int kbeg = ks*Kc, kend = min(Ktot, kbeg + Kc);
  int tm = tid >> 4, tn = tid & 15;
  float acc[4][4];
  #pragma unroll
  for (int i=0;i<4;i++){ acc[i][0]=0.f; acc[i][1]=0.f; acc[i][2]=0.f; acc[i][3]=0.f; }

  for (int k0 = kbeg; k0 < kend; k0 += 32){
    int klim = kend - k0; if (klim > 32) klim = 32;
    // A tile 64 x klim (load float4 over k, store transposed)
    #pragma unroll
    for (int i=0;i<2;i++){
      int idx = tid + i*256;           // float4 units over [64 m][8 kq]
      int m = idx >> 3, kq = (idx & 7) << 2;
      if (kq < klim){
        const float* ap = A + (size_t)(mb+m)*lda + k0 + kq;
        float4 v;
        if (kq + 3 < klim) v = *(const float4*)ap;
        else { v.x=ap[0]; v.y=(kq+1<klim)?ap[1]:0.f; v.z=(kq+2<klim)?ap[2]:0.f; v.w=0.f; }
        float* as = As + m;
        as[(kq+0)*68]=v.x; as[(kq+1)*68]=v.y; as[(kq+2)*68]=v.z; as[(kq+3)*68]=v.w;
      }
    }
    // B tile klim x 64
    #pragma unroll
    for (int i=0;i<2;i++){
      int idx = tid + i*256;           // float4 units over [32 kk][16 nq]
      int kk = idx >> 4, nq = (idx & 15) << 2;
      int n = nb + nq;
      float4 v = {0.f,0.f,0.f,0.f};
      if (kk < klim && n < N){
        const float* bp = B + (size_t)(k0+kk)*N + n;
        if (n + 3 < N) v = *(const float4*)bp;
        else { v.x=bp[0]; v.y=(n+1<N)?bp[1]:0.f; v.z=(n+2<N)?bp[2]:0.f; }
      }
      *(float4*)(Bs + kk*68 + nq) = v;
    }
    __syncthreads();
    for (int kk = 0; kk < klim; kk++){
      float4 a = *(const float4*)(As + kk*68 + tm*4);
      float4 bv = *(const float4*)(Bs + kk*68 + tn*4);
      acc[0][0]+=a.x*bv.x; acc[0][1]+=a.x*bv.y; acc[0][2]+=a.x*bv.z; acc[0][3]+=a.x*bv.w;
      acc[1][0]+=a.y*bv.x; acc[1][1]+=a.y*bv.y; acc[1][2]+=a.y*bv.z; acc[1][3]+=a.y*bv.w;
      acc[2][0]+=a.z*bv.x; acc[2][1]+=a.z*bv.y; acc[2][2]+=a.z*bv.z; acc[2][3]+=a.z*bv.w;
      acc[3][0]+=a.w*bv.x; acc[3][1]+=a.w*bv.y; acc[3][2]+=a.w*bv.z; acc[3][3]+=a.w*bv.w;
    }
    __syncthreads();
  }

  #pragma unroll
  for (int i=0;i<4;i++){
    int m = tm*4 + i;
    #pragma unroll
    for (int j=0;j<4;j++){
      int n = nb + tn*4 + j;
      if (n < N){
        if (mode == 0){
          part[((size_t)(ks*64 + m))*N + n] = acc[i][j];
        } else {
          float v = acc[i][j] + (bias ? bias[n] : 0.f);
          if (mode == 2) v = tanhf(v);
          out[(size_t)(mb+m)*N + n] = v;
        }
      }
    }
  }
}

// ------------------------- split-K reduce (+bias, optional tanh), float4 ----------
__global__ void reduce64(const float* __restrict__ part, int KS, int MN4, int N,
                         const float* __restrict__ bias, float* __restrict__ out, int mode){
  int idx = blockIdx.x*256 + threadIdx.x;
  if (idx >= MN4) return;
  int base = idx*4;
  int n = base % N;
  float4 s = {0.f,0.f,0.f,0.f};
  size_t stride = (size_t)MN4*4;
  for (int p=0;p<KS;p++){
    float4 t = *(const float4*)(part + (size_t)p*stride + base);
    s.x+=t.x; s.y+=t.y; s.z+=t.z; s.w+=t.w;
  }
  if (bias){
    float4 bb = *(const float4*)(bias + n);
    s.x+=bb.x; s.y+=bb.y; s.z+=bb.z; s.w+=bb.w;
  }
  if (mode == 1){ s.x=tanhf(s.x); s.y=tanhf(s.y); s.z=tanhf(s.z); s.w=tanhf(s.w); }
  *(float4*)(out + base) = s;
}

// ------------------------- comb = tanh(l2norm(imgf) * qsum/20) --------------------
__global__ __launch_bounds__(256) void comb_kernel(const float* __restrict__ imgf,
                                                   const float* __restrict__ qsum,
                                                   float* __restrict__ comb){
  __shared__ float s_red[4];
  int b = blockIdx.x, tid = threadIdx.x;
  float ss = 0.f;
  for (int j = tid; j < 1024; j += 256){ float v = imgf[b*1024+j]; ss += v*v; }
  ss = wave_sum64(ss);
  if ((tid & 63) == 0) s_red[tid>>6] = ss;
  __syncthreads();
  float inv = 1.0f / sqrtf(s_red[0]+s_red[1]+s_red[2]+s_red[3]);
  for (int j = tid; j < 1024; j += 256)
    comb[b*1024+j] = tanhf(imgf[b*1024+j]*inv * qsum[b*1024+j]*0.05f);
}

// ------------------------- last[:,1024:1280] = tanh(rvecT^T) ----------------------
__global__ void tanhrvec_kernel(const float* __restrict__ rvecT, float* __restrict__ lastB){
  int idx = blockIdx.x*256 + threadIdx.x;
  if (idx >= 16384) return;
  int b = idx & 63, i = idx >> 6;
  lastB[(size_t)b*1280 + 1024 + i] = tanhf(rvecT[i*64 + b]);
}

// ===================== persistent DNC recurrence kernel ===========================
struct SG_t { float Bs[768*8]; };
struct SO_t { float Bs[768*4]; };
struct SI_t { float Bs[512*4]; };
struct SD_t {
  float s_rk[256], s_rstr[4], s_wkey[64], s_erase[64], s_wvec[64];
  float s_free[4], s_modes[12], s_scal[3];
  float s_wr[1024], s_vB[1024];
  float s_wwold[256], s_wwnew[256], s_usage[256], s_prec[256];
  float s_alloc[256], s_scan[256];
  int   s_rank[256];
  float s_sim[1024];
  float s_fwA[1024], s_fwB[1024], s_C[1024], s_D[1024];
  float s_red[4];
  float s_PQ[8];
};
union SU_t { SG_t g; SO_t o; SI_t i; SD_t d; };

__device__ __forceinline__ void gbar(int* cnt, int epoch){
  __syncthreads();
  if (threadIdx.x == 0){
    __threadfence();
    atomicAdd(cnt, 1);
    int target = 256*epoch;
    while (atomicAdd(cnt, 0) < target) __builtin_amdgcn_s_sleep(2);
    __threadfence();
  }
  __syncthreads();
}

__device__ __forceinline__ float phaseO_val(int bid, int b_, int q_, int tid,
    const float* __restrict__ hcT_p, const float* __restrict__ rvecT,
    const float* __restrict__ Wout, const float* __restrict__ bout, float* BsO){
  int c0 = bid*4;
  for (int e = tid; e < 3072; e += 256){
    int k = e >> 2, c = e & 3;
    BsO[e] = Wout[(size_t)k*1024 + c0 + c];
  }
  __syncthreads();
  int col = c0 + q_;
  float acc = bout[col];
  #pragma unroll 8
  for (int k=0;k<512;k++) acc += hcT_p[k*64+b_] * BsO[k*4+q_];
  #pragma unroll 8
  for (int k=0;k<256;k++) acc += rvecT[k*64+b_] * BsO[(512+k)*4+q_];
  __syncthreads();
  return clipf_(acc);
}

__global__ __launch_bounds__(256) void dnc_recur(
    int T, int outmode,
    const float* __restrict__ gxp, const float* __restrict__ Wih_r,
    const float* __restrict__ Whh, const float* __restrict__ gb,
    const float* __restrict__ Wif, const float* __restrict__ bif,
    const float* __restrict__ Wout, const float* __restrict__ bout,
    float* __restrict__ ws, float* __restrict__ outbuf, int* __restrict__ bar)
{
  __shared__ SU_t su;
  __shared__ float s_g[512];

  float* memS  = ws + WS_MEM;
  float* linkS = ws + WS_LINK;
  float* precB = ws + WS_PREC;
  float* wrS   = ws + WS_WR;
  float* wwS   = ws + WS_WW;
  float* usgS  = ws + WS_USAGE;
  float* rvecT = ws + WS_RVECT;
  float* hT    = ws + WS_HT;
  float* hcT   = ws + WS_HCT;
  float* xiS   = ws + WS_XI;

  int tid = threadIdx.x, bid = blockIdx.x;
  int lane = tid & 63, wid = tid >> 6;
  int b_ = tid & 63, q_ = tid >> 6;
  float c_reg = 0.f;         // LSTM cell state for (b_, col=bid*2+q_) when tid<128
  float qacc = 0.f;          // qsum accumulator for (b_, col=bid*4+q_)
  float lastv = 0.f;
  int epoch = 0;

  for (int t = 0; t < T; t++){
    int pp = t & 1, wp = (t + 1) & 1;

    // ======== phase GLO: O(t-1) + gates(t) + LSTM(t) ========
    if (t > 0){
      float v = phaseO_val(bid, b_, q_, tid, hcT + pp*32768, rvecT, Wout, bout, su.o.Bs);
      qacc += v;   // outmode 0 path (mode 1 has T==1, never here)
    }
    {
      // load B: 8 cols (4 gates x 2 lstm-cols)
      int c2 = bid*2;
      for (int e = tid; e < 768*8; e += 256){
        int k = e >> 3, c8 = e & 7;
        int n = (c8 >> 1)*512 + c2 + (c8 & 1);
        su.g.Bs[e] = (k < 256) ? Wih_r[(size_t)k*2048 + n] : Whh[(size_t)(k-256)*2048 + n];
      }
      __syncthreads();
      int n0 = q_*512 + c2;
      float2 gv = *(const float2*)(gxp + ((size_t)(t*64 + b_))*2048 + n0);
      float acc0 = gb[n0]   + gv.x;
      float acc1 = gb[n0+1] + gv.y;
      const float* Ah = hT + pp*32768;
      const float2* Bs2 = (const float2*)su.g.Bs;
      #pragma unroll 8
      for (int k=0;k<256;k++){
        float a = rvecT[k*64 + b_];
        float2 w = Bs2[k*4 + q_];
        acc0 += a*w.x; acc1 += a*w.y;
      }
      #pragma unroll 8
      for (int k=0;k<512;k++){
        float a = Ah[k*64 + b_];
        float2 w = Bs2[(256+k)*4 + q_];
        acc0 += a*w.x; acc1 += a*w.y;
      }
      s_g[b_*8 + q_*2 + 0] = acc0;
      s_g[b_*8 + q_*2 + 1] = acc1;
      __syncthreads();
      if (tid < 128){
        int jj = q_;
        float gi = s_g[b_*8 + 0 + jj], gf = s_g[b_*8 + 2 + jj];
        float gg = s_g[b_*8 + 4 + jj], go = s_g[b_*8 + 6 + jj];
        float cn = sigmoidf_(gf)*c_reg + sigmoidf_(gi)*tanhf(gg);
        float hn = sigmoidf_(go)*tanhf(cn);
        c_reg = cn;
        int col = bid*2 + jj;
        hT [wp*32768 + col*64 + b_] = hn;
        hcT[wp*32768 + col*64 + b_] = clipf_(hn);
      }
    }
    epoch++; gbar(bar, epoch);

    // ======== phase I: xi = hc @ Wif + bif ========
    if (bid < 118){
      int c0 = bid*4;
      for (int e = tid; e < 2048; e += 256){
        int k = e >> 2, c = e & 3;
        int col = c0 + c;
        su.i.Bs[e] = (col < 471) ? Wif[(size_t)k*471 + col] : 0.f;
      }
      __syncthreads();
      int col = c0 + q_;
      if (col < 471){
        float acc = bif[col];
        const float* Ahc = hcT + wp*32768;
        #pragma unroll 8
        for (int k=0;k<512;k++) acc += Ahc[k*64+b_] * su.i.Bs[k*4+q_];
        xiS[b_*471 + col] = acc;
      }
      __syncthreads();
    }
    epoch++; gbar(bar, epoch);

    // ======== phase D: DNC memory step (blocks 0..63, one per sample) ========
    if (bid < 64){
      SD_t& sd = su.d;
      int b = bid;
      const float* prec_in  = precB + pp*16384;
      float*       prec_out = precB + wp*16384;

      // ---- Stage 1: parse interface vector, load states, zero C/D ----
      const float* xrow = xiS + (size_t)b*471;
      for (int idx = tid; idx < 471; idx += 256){
        float v = xrow[idx];
        if (idx < 256)       sd.s_rk[idx] = tanhf(v);
        else if (idx < 260)  sd.s_rstr[idx-256] = softplusf_(v);
        else if (idx < 324)  sd.s_wkey[idx-260] = v;
        else if (idx == 324) sd.s_scal[0] = softplusf_(v);
        else if (idx < 389)  sd.s_erase[idx-325] = sigmoidf_(v);
        else if (idx < 453)  sd.s_wvec[idx-389] = tanhf(v);
        else if (idx < 457)  sd.s_free[idx-453] = sigmoidf_(v);
        else if (idx == 457) sd.s_scal[1] = sigmoidf_(v);
        else if (idx == 458) sd.s_scal[2] = sigmoidf_(v);
        else                 sd.s_modes[idx-459] = v;
      }
      for (int e = tid; e < 1024; e += 256){
        sd.s_wr[e] = wrS[(size_t)b*1024 + e];
        sd.s_C[e] = 0.f; sd.s_D[e] = 0.f;
      }
      sd.s_wwold[tid] = wwS[(size_t)b*256 + tid];
      sd.s_usage[tid] = usgS[(size_t)b*256 + tid];
      sd.s_prec[tid]  = prec_in[(size_t)b*256 + tid];
      __syncthreads();

      if (tid < 4){
        float m0 = sd.s_modes[tid*3], m1 = sd.s_modes[tid*3+1], m2 = sd.s_modes[tid*3+2];
        float mx = fmaxf(m0, fmaxf(m1,m2));
        float e0 = expf(m0-mx), e1 = expf(m1-mx), e2 = expf(m2-mx);
        float s = e0+e1+e2;
        sd.s_modes[tid*3] = e0/s; sd.s_modes[tid*3+1] = e1/s; sd.s_modes[tid*3+2] = e2/s;
      }
      {
        float k = sd.s_rk[wid*64 + lane];
        float ss = wave_sum64(k*k);
        sd.s_rk[wid*64 + lane] = k / (sqrtf(ss) + EPSV);
      }
      if (wid == 0){
        float k = sd.s_wkey[lane];
        float ss = wave_sum64(k*k);
        sd.s_wkey[lane] = k / (sqrtf(ss) + EPSV);
      }

      // ---- Stage 2: usage update ----
      {
        float psi = 1.f;
        #pragma unroll
        for (int r=0;r<4;r++) psi *= (1.f - sd.s_free[r]*sd.s_wr[r*256+tid]);
        float u = (sd.s_usage[tid] + sd.s_wwold[tid] - sd.s_usage[tid]*sd.s_wwold[tid]) * psi;
        sd.s_usage[tid] = u;
        usgS[(size_t)b*256 + tid] = u;
      }
      __syncthreads();

      // ---- Stage 3: stable ascending rank ----
      {
        float u = sd.s_usage[tid];
        int rank = 0;
        for (int j=0;j<256;j++){
          float uj = sd.s_usage[j];
          rank += (uj < u) || (uj == u && j < tid);
        }
        sd.s_rank[tid] = rank;
        sd.s_scan[rank] = u;
      }
      __syncthreads();

      // ---- Stage 4: inclusive product scan ----
      for (int off=1; off<256; off<<=1){
        float tv = (tid >= off) ? sd.s_scan[tid-off] : 1.f;
        __syncthreads();
        sd.s_scan[tid] *= tv;
        __syncthreads();
      }
      {
        float u = sd.s_usage[tid];
        int rk = sd.s_rank[tid];
        float cpe = (rk > 0) ? sd.s_scan[rk-1] : 1.f;
        sd.s_alloc[tid] = (1.f - u) * cpe;
      }

      // ---- Stage 5: write-key cosine ----
      for (int i = 0; i < 64; i++){
        int n = wid*64 + i;
        float m = memS[(size_t)b*16384 + (size_t)n*64 + lane];
        float s1 = wave_sum64(m*m);
        float s2 = wave_sum64(m*sd.s_wkey[lane]);
        if (lane == 0) sd.s_sim[n] = s2 / (sqrtf(s1)+EPSV) * sd.s_scal[0];
      }
      __syncthreads();

      // ---- Stage 6: write softmax, ww, prec, vB, P, Q ----
      {
        float v = sd.s_sim[tid];
        float mx = block_max256(v, sd.s_red);
        float e = expf(v - mx);
        float sm = block_sum256(e, sd.s_red);
        float cw = e / sm;
        float wwn = sd.s_scal[2] * (sd.s_scal[1]*sd.s_alloc[tid] + (1.f - sd.s_scal[1])*cw);
        sd.s_wwnew[tid] = wwn;
        wwS[(size_t)b*256 + tid] = wwn;
        #pragma unroll
        for (int r=0;r<4;r++) sd.s_vB[r*256+tid] = wwn * sd.s_wr[r*256+tid];
        float wws = block_sum256(wwn, sd.s_red);
        prec_out[(size_t)b*256 + tid] = (1.f - wws)*sd.s_prec[tid] + wwn;
        #pragma unroll
        for (int r=0;r<4;r++){
          float pv  = block_sum256(sd.s_prec[tid]*sd.s_wr[r*256+tid], sd.s_red);
          float qv_ = block_sum256(wwn*sd.s_wr[r*256+tid], sd.s_red);
          if (tid == 0){ sd.s_PQ[r] = pv; sd.s_PQ[4+r] = qv_; }
        }
      }
      __syncthreads();

      // ---- Stage 7: memory update ----
      {
        float4* mem4 = (float4*)(memS + (size_t)b*16384);
        for (int e4 = tid; e4 < 4096; e4 += 256){
          int n = e4 >> 4;
          int w0 = (e4 & 15) << 2;
          float4 mv = mem4[e4];
          float wwn = sd.s_wwnew[n];
          mv.x = mv.x*(1.f - wwn*sd.s_erase[w0+0]) + wwn*sd.s_wvec[w0+0];
          mv.y = mv.y*(1.f - wwn*sd.s_erase[w0+1]) + wwn*sd.s_wvec[w0+1];
          mv.z = mv.z*(1.f - wwn*sd.s_erase[w0+2]) + wwn*sd.s_wvec[w0+2];
          mv.w = mv.w*(1.f - wwn*sd.s_erase[w0+3]) + wwn*sd.s_wvec[w0+3];
          mem4[e4] = mv;
        }
      }
      __syncthreads();

      // ---- Stage 8a: A,B row-sums vs OLD link ----
      {
        const float4* Lrow = (const float4*)(linkS + (size_t)b*65536 + (size_t)tid*256);
        float aA[4] = {0,0,0,0}, aB[4] = {0,0,0,0};
        for (int c4 = 0; c4 < 64; c4++){
          float4 lv = Lrow[c4];
          int j = c4*4;
          #pragma unroll
          for (int r=0;r<4;r++){
            aA[r] += lv.x*sd.s_wr[r*256+j] + lv.y*sd.s_wr[r*256+j+1] + lv.z*sd.s_wr[r*256+j+2] + lv.w*sd.s_wr[r*256+j+3];
            aB[r] += lv.x*sd.s_vB[r*256+j] + lv.y*sd.s_vB[r*256+j+1] + lv.z*sd.s_vB[r*256+j+2] + lv.w*sd.s_vB[r*256+j+3];
          }
        }
        #pragma unroll
        for (int r=0;r<4;r++){ sd.s_fwA[r*256+tid] = aA[r]; sd.s_fwB[r*256+tid] = aB[r]; }
      }
      __syncthreads();

      // ---- Stage 8b: link update + C,D col-sums ----
      {
        int cg = tid & 63, ioff = tid >> 6;
        int j0 = cg*4;
        float wwj0 = sd.s_wwnew[j0], wwj1 = sd.s_wwnew[j0+1], wwj2 = sd.s_wwnew[j0+2], wwj3 = sd.s_wwnew[j0+3];
        float pj0 = sd.s_prec[j0], pj1 = sd.s_prec[j0+1], pj2 = sd.s_prec[j0+2], pj3 = sd.s_prec[j0+3];
        float cC[4][4] = {{0}}, cD[4][4] = {{0}};
        float4* Lb = (float4*)(linkS + (size_t)b*65536);
        for (int it = 0; it < 64; it++){
          int i = it*4 + ioff;
          float4 lv = Lb[(size_t)i*64 + cg];
          float wwi = sd.s_wwnew[i];
          float4 ln;
          ln.x = (1.f - wwi - wwj0)*lv.x + wwi*pj0;
          ln.y = (1.f - wwi - wwj1)*lv.y + wwi*pj1;
          ln.z = (1.f - wwi - wwj2)*lv.z + wwi*pj2;
          ln.w = (1.f - wwi - wwj3)*lv.w + wwi*pj3;
          if (i >= j0 && i < j0+4){
            if (i == j0)        ln.x = 0.f;
            else if (i == j0+1) ln.y = 0.f;
            else if (i == j0+2) ln.z = 0.f;
            else                ln.w = 0.f;
          }
          Lb[(size_t)i*64 + cg] = ln;
          #pragma unroll
          for (int r=0;r<4;r++){
            float wri = sd.s_wr[r*256+i], vbi = sd.s_vB[r*256+i];
            cC[r][0] += lv.x*wri; cC[r][1] += lv.y*wri; cC[r][2] += lv.z*wri; cC[r][3] += lv.w*wri;
            cD[r][0] += lv.x*vbi; cD[r][1] += lv.y*vbi; cD[r][2] += lv.z*vbi; cD[r][3] += lv.w*vbi;
          }
        }
        for (int w=0; w<4; w++){
          if (ioff == w){
            #pragma unroll
            for (int r=0;r<4;r++){
              sd.s_C[r*256+j0+0] += cC[r][0]; sd.s_C[r*256+j0+1] += cC[r][1];
              sd.s_C[r*256+j0+2] += cC[r][2]; sd.s_C[r*256+j0+3] += cC[r][3];
              sd.s_D[r*256+j0+0] += cD[r][0]; sd.s_D[r*256+j0+1] += cD[r][1];
              sd.s_D[r*256+j0+2] += cD[r][2]; sd.s_D[r*256+j0+3] += cD[r][3];
            }
          }
          __syncthreads();
        }
      }

      // ---- Stage 9: read-key cosine on updated mem ----
      {
        const float4* Mrow = (const float4*)(memS + (size_t)b*16384 + (size_t)tid*64);
        float nrm2 = 0.f, d0=0.f, d1=0.f, d2=0.f, d3=0.f;
        for (int c4=0; c4<16; c4++){
          float4 mv = Mrow[c4];
          int w0 = c4*4;
          nrm2 += mv.x*mv.x + mv.y*mv.y + mv.z*mv.z + mv.w*mv.w;
          d0 += mv.x*sd.s_rk[w0] + mv.y*sd.s_rk[w0+1] + mv.z*sd.s_rk[w0+2] + mv.w*sd.s_rk[w0+3];
          d1 += mv.x*sd.s_rk[64+w0] + mv.y*sd.s_rk[64+w0+1] + mv.z*sd.s_rk[64+w0+2] + mv.w*sd.s_rk[64+w0+3];
          d2 += mv.x*sd.s_rk[128+w0] + mv.y*sd.s_rk[128+w0+1] + mv.z*sd.s_rk[128+w0+2] + mv.w*sd.s_rk[128+w0+3];
          d3 += mv.x*sd.s_rk[192+w0] + mv.y*sd.s_rk[192+w0+1] + mv.z*sd.s_rk[192+w0+2] + mv.w*sd.s_rk[192+w0+3];
        }
        float inv = 1.f/(sqrtf(nrm2)+EPSV);
        sd.s_sim[0*256+tid] = d0*inv*sd.s_rstr[0];
        sd.s_sim[1*256+tid] = d1*inv*sd.s_rstr[1];
        sd.s_sim[2*256+tid] = d2*inv*sd.s_rstr[2];
        sd.s_sim[3*256+tid] = d3*inv*sd.s_rstr[3];
      }
      __syncthreads();
      for (int r=0;r<4;r++){
        float v = sd.s_sim[r*256+tid];
        float mx = block_max256(v, sd.s_red);
        float e = expf(v - mx);
        float sm = block_sum256(e, sd.s_red);
        sd.s_sim[r*256+tid] = e/sm;
      }
      __syncthreads();

      // ---- Stage 10: fw/bw assembly + wr update ----
      {
        float wwn = sd.s_wwnew[tid], pn = sd.s_prec[tid];
        #pragma unroll
        for (int r=0;r<4;r++){
          float wro = sd.s_wr[r*256+tid];
          float fw  = (1.f-wwn)*sd.s_fwA[r*256+tid] - sd.s_fwB[r*256+tid] + wwn*(sd.s_PQ[r] - pn*wro);
          float bwv = (1.f-wwn)*sd.s_C[r*256+tid]   - sd.s_D[r*256+tid]   + pn*(sd.s_PQ[4+r] - wwn*wro);
          float wrn = sd.s_modes[r*3+0]*bwv + sd.s_modes[r*3+1]*sd.s_sim[r*256+tid] + sd.s_modes[r*3+2]*fw;
          wrS[(size_t)b*1024 + r*256 + tid] = wrn;
          sd.s_vB[r*256+tid] = wrn;
        }
      }
      __syncthreads();

      // ---- Stage 11: rvecT = (wr_new @ mem)^T ----
      {
        int r = tid >> 6, w = tid & 63;
        const float* Mb = memS + (size_t)b*16384;
        float acc = 0.f;
        for (int n=0; n<256; n++) acc += sd.s_vB[r*256+n]*Mb[(size_t)n*64 + w];
        rvecT[(r*64 + w)*64 + b] = acc;
      }
    }
    epoch++; gbar(bar, epoch);
  }

  // ======== final O(T-1) ========
  {
    float v = phaseO_val(bid, b_, q_, tid, hcT + (T&1)*32768, rvecT, Wout, bout, su.o.Bs);
    if (outmode == 0){
      qacc += v;
      outbuf[(size_t)b_*1024 + (bid*4 + q_)] = qacc;
    } else {
      outbuf[(size_t)b_*1280 + (bid*4 + q_)] = tanhf(v);
    }
  }
}

// ======================================================================================
extern "C" void kernel_launch(void* const* d_in, const int* in_sizes, int n_in,
                              void* d_out, int out_size, void* d_ws, size_t ws_size,
                              hipStream_t stream) {
  const float* img_feat = (const float*)d_in[0];
  const int*   qst      = (const int*)  d_in[1];
  const float* emb      = (const float*)d_in[2];
  const float* img_W    = (const float*)d_in[3];
  const float* img_b    = (const float*)d_in[4];
  const float* q_Wih    = (const float*)d_in[5];
  const float* q_Whh    = (const float*)d_in[6];
  const float* q_b      = (const float*)d_in[7];
  const float* q_Wif    = (const float*)d_in[8];
  const float* q_bif    = (const float*)d_in[9];
  const float* q_Wout   = (const float*)d_in[10];
  const float* q_bout   = (const float*)d_in[11];
  const float* c_Wih    = (const float*)d_in[12];
  const float* c_Whh    = (const float*)d_in[13];
  const float* c_b      = (const float*)d_in[14];
  const float* c_Wif    = (const float*)d_in[15];
  const float* c_bif    = (const float*)d_in[16];
  const float* c_Wout   = (const float*)d_in[17];
  const float* c_bout   = (const float*)d_in[18];
  const float* fc1_W    = (const float*)d_in[19];
  const float* fc1_b    = (const float*)d_in[20];
  const float* fc2_W    = (const float*)d_in[21];
  const float* fc2_b    = (const float*)d_in[22];

  float* ws = (float*)d_ws;
  float* qv    = ws + WS_QV;
  float* zoneC = ws + WS_ZONEC;
  float* imgf  = ws + WS_IMGF;
  float* combB = ws + WS_COMB;
  float* lastB = ws + WS_LASTB;
  float* hid1  = ws + WS_HID1;
  float* qsum  = ws + WS_QSUM;
  int*   bar   = (int*)(ws + WS_BAR);

  // zero state zone (incl. barrier counter, qsum)
  hipMemsetAsync(ws, 0, (size_t)WS_ZONEA*4, stream);

  // qv[(t*64+b)][300] = tanh(emb[qst])
  embed_kernel<<<1500, 256, 0, stream>>>(qst, emb, qv);

  // image fc: imgf = img_feat @ img_W + img_b  (split-K 16)
  gemm64<<<dim3(16,16,1), 256, 0, stream>>>(64, 1024, 4096, 16,
      img_feat, 4096, img_W, nullptr, nullptr, zoneC, 0);
  reduce64<<<64, 256, 0, stream>>>(zoneC, 16, 16384, 1024, img_b, imgf, 0);

  // gxp = qv @ q_Wih[0:300]  (M=1280, plain)
  gemm64<<<dim3(32,1,20), 256, 0, stream>>>(1280, 2048, 300, 1,
      qv, 300, q_Wih, nullptr, zoneC, nullptr, 1);

  // question DNC, 20 steps (persistent)
  dnc_recur<<<256, 256, 0, stream>>>(20, 0,
      zoneC, q_Wih + (size_t)300*2048, q_Whh, q_b,
      q_Wif, q_bif, q_Wout, q_bout, ws, qsum, bar);

  // comb = tanh(l2norm(imgf) * qsum/20)
  comb_kernel<<<64, 256, 0, stream>>>(imgf, qsum, combB);

  // reset state zone for controller
  hipMemsetAsync(ws, 0, (size_t)WS_ZONEA*4, stream);

  // cxp = comb @ c_Wih[0:1024]  (split-K 4)
  float* cxp  = zoneC;
  float* cxpP = zoneC + 131072;
  gemm64<<<dim3(32,4,1), 256, 0, stream>>>(64, 2048, 1024, 4,
      combB, 1024, c_Wih, nullptr, nullptr, cxpP, 0);
  reduce64<<<128, 256, 0, stream>>>(cxpP, 4, 32768, 2048, nullptr, cxp, 0);

  // controller DNC, 1 step (persistent) -> lastB[:, :1024] = tanh(clip(out_c))
  dnc_recur<<<256, 256, 0, stream>>>(1, 1,
      cxp, c_Wih + (size_t)1024*2048, c_Whh, c_b,
      c_Wif, c_bif, c_Wout, c_bout, ws, lastB, bar);

  // lastB[:, 1024:1280] = tanh(rvec_ctrl)
  tanhrvec_kernel<<<64, 256, 0, stream>>>(ws + WS_RVECT, lastB);

  // fc1: hid1 = tanh(lastB @ fc1_W + fc1_b)  (split-K 5)
  gemm64<<<dim3(47,5,1), 256, 0, stream>>>(64, 3000, 1280, 5,
      lastB, 1280, fc1_W, nullptr, nullptr, zoneC, 0);
  reduce64<<<188, 256, 0, stream>>>(zoneC, 5, 48000, 3000, fc1_b, hid1, 1);

  // fc2: logits = hid1 @ fc2_W + fc2_b  (split-K 6)
  gemm64<<<dim3(47,6,1), 256, 0, stream>>>(64, 3000, 3000, 6,
      hid1, 3000, fc2_W, nullptr, nullptr, zoneC, 0);
  reduce64<<<188, 256, 0, stream>>>(zoneC, 6, 48000, 3000, fc2_b, (float*)d_out, 0);
}